// Round 9
// baseline (906.357 us; speedup 1.0000x reference)
//
#include <hip/hip_runtime.h>
#include <cmath>

// ---------------------------------------------------------------------------
// SemanticFreeFuXiBlock on MI355X (gfx950), bf16 MFMA implementation.
// B=64, N=1024, D=512, H=8, LD=64, HIDDEN=2048, NB=128, T = in_sizes[0]/512.
// Round 9:
//  - GEMM K-loop widened to BK=64: 32 MFMAs per barrier pair (2x round 7),
//    LDS 34.8 KB/block (still 4 blocks/CU -> no occupancy cliff).
//  - attention reverted to round-7 form (in-kernel V scatter, flat grid);
//    vprep dropped (its 110 MB round-trip cost more than it saved).
//  - kept: XCD-grouped GEMM swizzle, AMODE staging fusions (native packed
//    cvt), u8 ts panels, row_ss, workspace plan.
// ---------------------------------------------------------------------------

using u16 = unsigned short;
using u8  = unsigned char;

typedef __bf16 bf16x8 __attribute__((ext_vector_type(8)));
typedef __bf16 bf16x2 __attribute__((ext_vector_type(2)));
typedef float  f32x4  __attribute__((ext_vector_type(4)));
typedef float  f32x2  __attribute__((ext_vector_type(2)));

#define TS_SCALE_F (float)(128.0 / 14.0)

__device__ __forceinline__ u16 f2b(float f) {            // RNE f32 -> bf16 bits
  unsigned u = __float_as_uint(f);
  unsigned r = 0x7FFFu + ((u >> 16) & 1u);
  return (u16)((u + r) >> 16);
}
__device__ __forceinline__ u16 f2b_n(float f) {          // native cvt (RNE)
  union { __bf16 b; u16 u; } c; c.b = (__bf16)f; return c.u;
}
__device__ __forceinline__ unsigned cvt_pk2(float a, float b) { // 2x f32->bf16
  f32x2 v; v[0] = a; v[1] = b;
  bf16x2 r = __builtin_convertvector(v, bf16x2);
  union { bf16x2 b; unsigned u; } c; c.b = r; return c.u;
}
__device__ __forceinline__ float b2f(u16 v) {
  return __uint_as_float(((unsigned)v) << 16);
}
__device__ __forceinline__ bf16x8 as_frag(uint4 r) {
  union { uint4 u; bf16x8 v; } c; c.u = r; return c.v;
}

// async global->LDS, 16 bytes per lane (lds dest: wave base + lane*16)
__device__ __forceinline__ void gload_lds16(const u16* g, u16* l) {
  __builtin_amdgcn_global_load_lds(
      (const __attribute__((address_space(1))) unsigned int*)g,
      (__attribute__((address_space(3))) unsigned int*)l, 16, 0, 0);
}

// ts u8 panel base (bytes): per batch 589824; per nt prefix nt*(nt+1)/2*16384.
__device__ __forceinline__ size_t ts_base_u8(int b, int nt) {
  return (size_t)b * 589824 + (size_t)(nt * (nt + 1) / 2) * 16384;
}

// ---------------------------------------------------------------------------
// Weight pre-transpose: W (KxN f32 row-major) -> Wp bf16 panels.
// Wp elem offset = ((p*(K/32)+s)*4 + kb)*1024 + c*8 + ke
//   holds W[s*32 + kb*8 + ke][p*128 + c].
// ---------------------------------------------------------------------------
__global__ __launch_bounds__(256) void wprep(
    const float* __restrict__ W, u16* __restrict__ Wp, int K, int N)
{
  const int p = blockIdx.x, s = blockIdx.y;
  const int t = threadIdx.x;
  size_t base = ((size_t)p * (K >> 5) + s) * 4096;
  const int e0 = t * 16;
  u16 o[16];
#pragma unroll
  for (int i = 0; i < 16; ++i) {
    int e = e0 + i;
    int kb = e >> 10, r = e & 1023, c = r >> 3, ke = r & 7;
    o[i] = f2b(W[(size_t)(s * 32 + kb * 8 + ke) * N + p * 128 + c]);
  }
  *(uint4*)(Wp + base + e0)     = *(uint4*)o;
  *(uint4*)(Wp + base + e0 + 8) = *(uint4*)(o + 8);
}

// ---------------------------------------------------------------------------
// Generic bf16 GEMM: C = epi(Asrc @ W), W pre-transposed to LDS image.
// Tile 128x128, BK=64: per round stage 128x64 A + 64x128 B, then 2x16 MFMA.
// 256 thr = 4 waves (2x2 of 64x64). Single-buffer, one barrier pair / round.
// 1-D grid with XCD-grouped swizzle (m204 bijective).
// AMODE: 0 = bf16 A; 1 = f32 A * inv[row]; 2 = bf16 A * inv[row] * bf16 U.
// ---------------------------------------------------------------------------
#define EPI_SILU_BF16 0
#define EPI_ADD_F32   1
#define AM_BF16   0
#define AM_F32S   1
#define AM_BF16SM 2

template <int EPI, int AMODE>
__global__ __launch_bounds__(256, 2) void gemm_bf16(
    const u16* __restrict__ A, const float* __restrict__ Af,
    const float* __restrict__ inv, const u16* __restrict__ U, int ustride,
    const u16* __restrict__ Wp, void* __restrict__ C,
    const float* __restrict__ ADD, int M, int N, int K, int ncb)
{
  __shared__ u16 lA[128 * 72];      // 128 rows x 64 k, pad to 72
  __shared__ u16 lB[8192];          // two 32-k image panels

  // XCD-grouped bijective swizzle (m204)
  const int nblk = gridDim.x;
  const int q = nblk >> 3, r = nblk & 7;
  const int xcd = blockIdx.x & 7, li = blockIdx.x >> 3;
  const int work = xcd * q + (xcd < r ? xcd : r) + li;
  const int c0b = work % ncb;
  const int t0  = (work / ncb) * 128;
  const int c0  = c0b * 128;

  const int tid  = threadIdx.x;
  const int wave = tid >> 6, lane = tid & 63;
  const int wr   = (wave >> 1) * 64, wc = (wave & 1) * 64;
  const int l15  = lane & 15, l4 = lane >> 4;

  f32x4 z = {0.f, 0.f, 0.f, 0.f};
  f32x4 acc[4][4];
#pragma unroll
  for (int m = 0; m < 4; ++m)
#pragma unroll
    for (int j = 0; j < 4; ++j) acc[m][j] = z;

  const int ar = tid >> 1, ak = (tid & 1) * 32;      // A stage: 32 elems along K
  const int row = t0 + ar;
  const bool arow_ok = row < M;
  float rinv = 0.f;
  if (AMODE != AM_BF16 && arow_ok) rinv = inv[row];
  const u16*   ab = (AMODE != AM_F32S) ? A + (size_t)row * K + ak : nullptr;
  const float* af = (AMODE == AM_F32S) ? Af + (size_t)row * K + ak : nullptr;
  const u16*   um = (AMODE == AM_BF16SM) ? U + (size_t)row * ustride + ak : nullptr;

  const int rounds = K >> 6;
  const u16* wsrc = Wp + (size_t)c0b * (K >> 5) * 4096 + wave * 2048 + lane * 8;
  u16* ldsb = &lB[wave * 2048];

  for (int s = 0; s < rounds; ++s) {
    const int k0 = s * 64;
    uint4 pr[8];
    const uint4 z4 = make_uint4(0, 0, 0, 0);
    if (!arow_ok) {
#pragma unroll
      for (int i = 0; i < 8; ++i) pr[i] = z4;
    } else if constexpr (AMODE == AM_BF16) {
#pragma unroll
      for (int i = 0; i < 4; ++i) pr[i] = *(const uint4*)(ab + k0 + 8 * i);
    } else if constexpr (AMODE == AM_F32S) {
#pragma unroll
      for (int i = 0; i < 8; ++i) pr[i] = *(const uint4*)(af + k0 + 4 * i);
    } else {
#pragma unroll
      for (int i = 0; i < 4; ++i) pr[i] = *(const uint4*)(ab + k0 + 8 * i);
#pragma unroll
      for (int i = 0; i < 4; ++i) pr[4 + i] = *(const uint4*)(um + k0 + 8 * i);
    }
    // B: async DMA, 4 x 1KB per wave (16 KB total)
    gload_lds16(wsrc,        ldsb);
    gload_lds16(wsrc + 512,  ldsb + 512);
    gload_lds16(wsrc + 1024, ldsb + 1024);
    gload_lds16(wsrc + 1536, ldsb + 1536);
    wsrc += 8192;
    // A: transform (native packed cvt) + vector LDS writes into padded rows
    {
      u16 tmp[32];
      unsigned* t32 = (unsigned*)tmp;
      if constexpr (AMODE == AM_BF16) {
#pragma unroll
        for (int i = 0; i < 4; ++i) *(uint4*)(tmp + 8 * i) = pr[i];
      } else if constexpr (AMODE == AM_F32S) {
        const float* f = (const float*)pr;
#pragma unroll
        for (int i = 0; i < 16; ++i)
          t32[i] = cvt_pk2(f[2 * i] * rinv, f[2 * i + 1] * rinv);
      } else {
        const u16* a = (const u16*)pr;
        const u16* u = (const u16*)(pr + 4);
#pragma unroll
        for (int i = 0; i < 16; ++i)
          t32[i] = cvt_pk2(b2f(a[2 * i]) * rinv * b2f(u[2 * i]),
                           b2f(a[2 * i + 1]) * rinv * b2f(u[2 * i + 1]));
      }
#pragma unroll
      for (int i = 0; i < 4; ++i)
        *(uint4*)&lA[ar * 72 + ak + 8 * i] = *(uint4*)(tmp + 8 * i);
    }
    __syncthreads();

#pragma unroll
    for (int ks = 0; ks < 2; ++ks) {
      bf16x8 afr[4], bfv[4];
#pragma unroll
      for (int m = 0; m < 4; ++m)
        afr[m] = as_frag(*(const uint4*)&lA[(wr + m * 16 + l15) * 72 + ks * 32 + l4 * 8]);
#pragma unroll
      for (int j = 0; j < 4; ++j)
        bfv[j] = as_frag(*(const uint4*)&lB[ks * 4096 + (l4 << 10) + (wc + j * 16 + l15) * 8]);
#pragma unroll
      for (int m = 0; m < 4; ++m)
#pragma unroll
        for (int j = 0; j < 4; ++j)
          acc[m][j] = __builtin_amdgcn_mfma_f32_16x16x32_bf16(afr[m], bfv[j], acc[m][j], 0, 0, 0);
    }
    __syncthreads();
  }

#pragma unroll
  for (int m = 0; m < 4; ++m) {
#pragma unroll
    for (int rr = 0; rr < 4; ++rr) {
      int orow = t0 + wr + m * 16 + l4 * 4 + rr;
      if (orow >= M) continue;
#pragma unroll
      for (int j = 0; j < 4; ++j) {
        int col = c0 + wc + j * 16 + l15;
        size_t idx = (size_t)orow * N + col;
        float y = acc[m][j][rr];
        if constexpr (EPI == EPI_SILU_BF16) {
          float s = y / (1.f + __expf(-y));          // silu
          ((u16*)C)[idx] = f2b_n(s);
        } else {
          ((float*)C)[idx] = y + ADD[idx];
        }
      }
    }
  }
}

// ---------------------------------------------------------------------------
// pos score table: pos_s[n][m] = pos_w[n-m+1023] * (m<=n), bf16, 1024x1024.
// ---------------------------------------------------------------------------
__global__ __launch_bounds__(128) void pos_scores(
    const float* __restrict__ pos_w, u16* __restrict__ pos_s)
{
  const int n = blockIdx.x;
  const int m0 = threadIdx.x * 8;
  u16 o[8];
#pragma unroll
  for (int i = 0; i < 8; ++i) {
    int m = m0 + i;
    float v = (m <= n) ? pos_w[n - m + 1023] : 0.f;
    o[i] = f2b(v);
  }
  *(uint4*)(pos_s + (size_t)n * 1024 + m0) = *(uint4*)o;
}

// ---------------------------------------------------------------------------
// ts bucket panels (u8): for (b, nt), 128 rows x W cols, W = 128*(nt+1):
//   bucket = clip(floor(log1p|dt|*SCALE),0,128); masked (m>n) -> 129.
// ---------------------------------------------------------------------------
__global__ __launch_bounds__(256) void ts_buckets(
    const int* __restrict__ tstamp, u8* __restrict__ ts_s)
{
  const int nt = 7 - (blockIdx.x >> 6);
  const int b  = blockIdx.x & 63;
  const int W  = 128 * (nt + 1);
  const int n0 = nt * 128;
  const int tid = threadIdx.x;

  __shared__ int tsm[1024];
  for (int i = tid; i < W; i += 256) tsm[i] = tstamp[b * 1024 + i];
  __syncthreads();

  const int r = tid >> 1, h = tid & 1;
  const int n_abs = n0 + r;
  const int t_n = tstamp[b * 1024 + n_abs];
  const int half = W >> 1;
  const int c0 = h * half;
  u8* row = ts_s + ts_base_u8(b, nt) + (size_t)r * W + c0;

  for (int c = 0; c < half; c += 16) {
    u8 o[16];
#pragma unroll
    for (int i = 0; i < 16; ++i) {
      int m = c0 + c + i;
      int d = t_n - tsm[m];
      if (d < 0) d = -d;
      int bkt = (int)(log1pf((float)d) * TS_SCALE_F);   // >=0: trunc == floor
      bkt = bkt > 128 ? 128 : bkt;
      o[i] = (m <= n_abs) ? (u8)bkt : (u8)129;
    }
    *(uint4*)(row + c) = *(uint4*)o;
  }
}

// ---------------------------------------------------------------------------
// Attention as dual GEMM (round-7 form): out_pos = pos_s @ V,
// out_ts = LUT(tsU8) @ V, V gathered from proj cols [1024,1536), ragged rows
// zeroed. Output bf16, head-interleaved layout, into ws.
// ---------------------------------------------------------------------------
__global__ __launch_bounds__(256, 1) void attn_gemm(
    const u16* __restrict__ proj,      // T x 1536 bf16
    const int* __restrict__ xoff,      // B+1 (int32)
    const u16* __restrict__ pos_s,     // 1024 x 1024 bf16
    const u8*  __restrict__ tsU8,      // u8 bucket panels
    const float* __restrict__ ts_w,    // 129
    u16* __restrict__ attn_out,        // T x 1024 bf16 (ws)
    int Ttot)
{
  const int flat = blockIdx.x;
  const int nt = 7 - (flat >> 8);          // heavy tiles dispatched first
  const int rem = flat & 255;
  const int b  = rem >> 2;
  const int ct = rem & 3;

  const int off = xoff[b];
  int len = xoff[b + 1] - off;
  if (len < 0) len = 0;
  if (len > 1024) len = 1024;
  if (off < 0 || off + len > Ttot) return;
  const int n0 = nt * 128;
  if (n0 >= len) return;
  const int c0 = ct * 128;
  const int W = 128 * (nt + 1);

  __shared__ u16 lP[128 * 40];
  __shared__ u16 lT[128 * 40];
  __shared__ u16 sV[4096];
  __shared__ float s_tsw[130];

  const int tid = threadIdx.x;
  if (tid < 130) s_tsw[tid] = (tid < 129) ? ts_w[tid] : 0.f;
  __syncthreads();

  const int wave = tid >> 6, lane = tid & 63;
  const int wr = (wave >> 1) * 64, wc = (wave & 1) * 64;
  const int l15 = lane & 15, l4 = lane >> 4;

  f32x4 z = {0.f, 0.f, 0.f, 0.f};
  f32x4 accP[4][4], accT[4][4];
#pragma unroll
  for (int m = 0; m < 4; ++m)
#pragma unroll
    for (int j = 0; j < 4; ++j) { accP[m][j] = z; accT[m][j] = z; }

  const int ar = tid >> 1, ak = (tid & 1) * 16;
  const u16* pRow = pos_s + (size_t)(n0 + ar) * 1024 + ak;
  const u8*  tRow = tsU8 + ts_base_u8(b, nt) + (size_t)ar * W + ak;
  const int vk = tid >> 3, vc = (tid & 7) * 16;

  const int mEnd = (n0 + 128 < len) ? (n0 + 128) : len;

  for (int m0 = 0; m0 < mEnd; m0 += 32) {
    // ---- stage V tile (32 x 128), transposed+swizzled, ragged-zeroed ----
    {
      int mm = m0 + vk;
      uint4 v0 = make_uint4(0, 0, 0, 0), v1 = v0;
      if (mm < len) {
        const u16* src = proj + (size_t)(off + mm) * 1536 + 1024 + c0 + vc;
        v0 = *(const uint4*)src;
        v1 = *(const uint4*)(src + 8);
      }
      u16 tmp[16];
      *(uint4*)tmp       = v0;
      *(uint4*)(tmp + 8) = v1;
      const int kb = vk >> 3, ke = vk & 7;
#pragma unroll
      for (int i = 0; i < 16; ++i) {
        int col = vc + i;
        int o2 = (kb * 2048 + col * 16 + ke * 2) ^ (((col >> 3) & 7) << 4);
        *(u16*)((char*)sV + o2) = tmp[i];
      }
    }
    // ---- stage score tiles: pos streamed bf16; ts via u8 + LDS LUT ----
    {
      uint4 p0 = *(const uint4*)(pRow + m0);
      uint4 p1 = *(const uint4*)(pRow + m0 + 8);
      uint4 tb = *(const uint4*)(tRow + m0);
      const u8* bp = (const u8*)&tb;
      unsigned tt32[8];
#pragma unroll
      for (int i = 0; i < 8; ++i)
        tt32[i] = cvt_pk2(s_tsw[bp[2 * i]], s_tsw[bp[2 * i + 1]]);
      int wb = ar * 40 + ak;
      *(uint4*)&lP[wb]     = p0;
      *(uint4*)&lP[wb + 8] = p1;
      *(uint4*)&lT[wb]     = *(uint4*)tt32;
      *(uint4*)&lT[wb + 8] = *(uint4*)(tt32 + 4);
    }
    __syncthreads();

    bf16x8 ap[4], at[4], bv[4];
#pragma unroll
    for (int m = 0; m < 4; ++m) {
      ap[m] = as_frag(*(const uint4*)&lP[(wr + m * 16 + l15) * 40 + l4 * 8]);
      at[m] = as_frag(*(const uint4*)&lT[(wr + m * 16 + l15) * 40 + l4 * 8]);
    }
#pragma unroll
    for (int j = 0; j < 4; ++j) {
      int col = wc + j * 16 + l15;
      int o2 = (l4 * 2048 + col * 16) ^ (((col >> 3) & 7) << 4);
      bv[j] = as_frag(*(const uint4*)((char*)sV + o2));
    }
#pragma unroll
    for (int m = 0; m < 4; ++m)
#pragma unroll
      for (int j = 0; j < 4; ++j) {
        accP[m][j] = __builtin_amdgcn_mfma_f32_16x16x32_bf16(ap[m], bv[j], accP[m][j], 0, 0, 0);
        accT[m][j] = __builtin_amdgcn_mfma_f32_16x16x32_bf16(at[m], bv[j], accT[m][j], 0, 0, 0);
      }
    __syncthreads();
  }

  // ---- store bf16 with head-interleaved combined layout ----
#pragma unroll
  for (int m = 0; m < 4; ++m)
#pragma unroll
    for (int r = 0; r < 4; ++r) {
      int n = n0 + wr + m * 16 + l4 * 4 + r;
      if (n >= len) continue;
      size_t t = (size_t)(off + n);
#pragma unroll
      for (int j = 0; j < 4; ++j) {
        int hd = c0 + wc + j * 16 + l15;            // 0..511
        int colP = ((hd >> 6) << 7) + (hd & 63);    // h*128 + d
        attn_out[t * 1024 + colP]      = f2b_n(accP[m][j][r]);
        attn_out[t * 1024 + colP + 64] = f2b_n(accT[m][j][r]);
      }
    }
}

// ---------------------------------------------------------------------------
// Per-row inv-rms: inv[row] = rsqrt(mean(row^2) + eps). 4 rows/block (1/wave).
// ---------------------------------------------------------------------------
template <int D, bool F32IN>
__global__ __launch_bounds__(256) void row_ss(
    const void* __restrict__ in, float* __restrict__ inv, int T)
{
  const int row = blockIdx.x * 4 + (threadIdx.x >> 6);
  const int lane = threadIdx.x & 63;
  if (row >= T) return;
  float ss = 0.f;
  if constexpr (F32IN) {
    const float* r = (const float*)in + (size_t)row * D;
#pragma unroll
    for (int i = lane * 4; i < D; i += 256) {
      float4 v = *(const float4*)(r + i);
      ss += v.x * v.x + v.y * v.y + v.z * v.z + v.w * v.w;
    }
  } else {
    const u16* r = (const u16*)in + (size_t)row * D;
#pragma unroll
    for (int i = lane * 8; i < D; i += 512) {
      uint4 v = *(const uint4*)(r + i);
      const u16* q = (const u16*)&v;
#pragma unroll
      for (int k = 0; k < 8; ++k) { float f = b2f(q[k]); ss += f * f; }
    }
  }
#pragma unroll
  for (int o = 32; o > 0; o >>= 1) ss += __shfl_down(ss, o, 64);
  if (lane == 0) inv[row] = rsqrtf(ss / (float)D + 1e-6f);
}

// ---------------------------------------------------------------------------
extern "C" void kernel_launch(void* const* d_in, const int* in_sizes, int n_in,
                              void* d_out, int out_size, void* d_ws, size_t ws_size,
                              hipStream_t stream)
{
  const float* x      = (const float*)d_in[0];
  const int*   xoff   = (const int*)d_in[1];    // int32 per harness contract
  const int*   tstamp = (const int*)d_in[2];    // int32 per harness contract
  // d_in[3] = invalid_attn_mask (tril) -- implied by causal masking, unused
  const float* uv     = (const float*)d_in[4];
  const float* pos_w  = (const float*)d_in[5];
  const float* ts_w   = (const float*)d_in[6];
  const float* w_ams  = (const float*)d_in[7];
  const float* w1     = (const float*)d_in[8];
  const float* w2     = (const float*)d_in[9];
  const int T = in_sizes[0] / 512;
  const int nrow = (T + 127) / 128;

  char* ws = (char*)d_ws;
  size_t o = 0;
  auto take = [&](size_t bytes) { size_t r = o; o += (bytes + 255) & ~(size_t)255; return r; };

  // --- static small buffers ---
  u16* uvb    = (u16*)(ws + take((size_t)512 * 1536 * 2));
  u16* wamsb  = (u16*)(ws + take((size_t)1024 * 512 * 2));
  u16* w1b    = (u16*)(ws + take((size_t)512 * 2048 * 2));
  u16* w2b    = (u16*)(ws + take((size_t)2048 * 512 * 2));
  u16* posS   = (u16*)(ws + take((size_t)1024 * 1024 * 2));   // 2 MB

  // --- main regions ---
  size_t o_ts   = take((size_t)64 * 589824 + 256); // tsU8 37.7 MB (+overread pad)
  size_t o_attn = take((size_t)T * 1024 * 2);      // attn bf16 83.9 [attn->F]
  size_t o_proj = take((size_t)T * 1536 * 2);      // proj 125.8 [B->F]
  float* invX = (float*)(ws + take((size_t)T * 4));
  float* invA = (float*)(ws + take((size_t)T * 4));
  float* invH = (float*)(ws + take((size_t)T * 4));

  u8*  tsU8  = (u8*)(ws + o_ts);
  u16* attnS = (u16*)(ws + o_attn);
  u16* proj  = (u16*)(ws + o_proj);
  u16* mid   = (u16*)(ws + o_ts);     // T x 2048 bf16 [H->I]; aliases
                                      // tsU8+attnS+proj-head (all dead by H)
  float* h   = (float*)d_out;         // h lives in d_out (F->I), out in-place

  // If the workspace is too small, launch nothing: clean absmax failure.
  if (ws_size < o) return;

  // weight pre-transpose f32 -> bf16 LDS-image panels
  wprep<<<dim3(12, 16), 256, 0, stream>>>(uv,    uvb,   512,  1536);
  wprep<<<dim3(4, 32),  256, 0, stream>>>(w_ams, wamsb, 1024, 512);
  wprep<<<dim3(16, 16), 256, 0, stream>>>(w1,    w1b,   512,  2048);
  wprep<<<dim3(4, 64),  256, 0, stream>>>(w2,    w2b,   2048, 512);

  // score precompute
  pos_scores<<<1024, 128, 0, stream>>>(pos_w, posS);
  ts_buckets<<<512, 256, 0, stream>>>(tstamp, tsU8);

  // invX over x
  row_ss<512, true><<<(T + 3) / 4, 256, 0, stream>>>(x, invX, T);

  // B: proj = silu((x*invX) @ uv)   (T x 1536)
  gemm_bf16<EPI_SILU_BF16, AM_F32S><<<12 * nrow, 256, 0, stream>>>(
      nullptr, x, invX, nullptr, 0, uvb, proj, nullptr, T, 1536, 512, 12);

  // attention -> attnS (ws)
  attn_gemm<<<64 * 32, 256, 0, stream>>>(proj, xoff, posS, tsU8, ts_w, attnS, T);

  // invA over attn
  row_ss<1024, false><<<(T + 3) / 4, 256, 0, stream>>>(attnS, invA, T);

  // F: h = x + ((attn*invA*u) @ w_ams)   (T x 512) -> d_out
  gemm_bf16<EPI_ADD_F32, AM_BF16SM><<<4 * nrow, 256, 0, stream>>>(
      attnS, nullptr, invA, proj, 1536, wamsb, h, x, T, 512, 1024, 4);

  // invH over h
  row_ss<512, true><<<(T + 3) / 4, 256, 0, stream>>>(h, invH, T);

  // H: mid = silu((h*invH) @ w1)   (T x 2048) -> aliased region
  gemm_bf16<EPI_SILU_BF16, AM_F32S><<<16 * nrow, 256, 0, stream>>>(
      nullptr, h, invH, nullptr, 0, w1b, mid, nullptr, T, 2048, 512, 16);

  // I: out = h + mid @ w2   (T x 512), in-place on d_out
  gemm_bf16<EPI_ADD_F32, AM_BF16><<<4 * nrow, 256, 0, stream>>>(
      mid, nullptr, nullptr, nullptr, 0, w2b, h, h, T, 512, 2048, 4);
}

// Round 10
// 834.027 us; speedup vs baseline: 1.0867x; 1.0867x over previous
//
#include <hip/hip_runtime.h>
#include <cmath>

// ---------------------------------------------------------------------------
// SemanticFreeFuXiBlock on MI355X (gfx950), bf16 MFMA implementation.
// B=64, N=1024, D=512, H=8, LD=64, HIDDEN=2048, NB=128, T = in_sizes[0]/512.
// Round 10:
//  - GEMM back to BK=32 single-buffer 2-barrier (round-7/8 proven structure).
//  - NEW AM_IMG A-mode: A pre-laid-out in MFMA image tiles -> staged with
//    global_load_lds (zero VALU). Used by:
//      B-GEMM: xb = bf16(x*invX) image written by row_ss (into d_out scratch)
//      I-GEMM: mid image written directly by H's epilogue (EPI_SILU_IMG)
//  - kept: XCD swizzle, native packed cvt, u8 ts panels, round-7 attention.
// ---------------------------------------------------------------------------

using u16 = unsigned short;
using u8  = unsigned char;

typedef __bf16 bf16x8 __attribute__((ext_vector_type(8)));
typedef __bf16 bf16x2 __attribute__((ext_vector_type(2)));
typedef float  f32x4  __attribute__((ext_vector_type(4)));
typedef float  f32x2  __attribute__((ext_vector_type(2)));

#define TS_SCALE_F (float)(128.0 / 14.0)

__device__ __forceinline__ u16 f2b(float f) {            // RNE f32 -> bf16 bits
  unsigned u = __float_as_uint(f);
  unsigned r = 0x7FFFu + ((u >> 16) & 1u);
  return (u16)((u + r) >> 16);
}
__device__ __forceinline__ u16 f2b_n(float f) {          // native cvt (RNE)
  union { __bf16 b; u16 u; } c; c.b = (__bf16)f; return c.u;
}
__device__ __forceinline__ unsigned cvt_pk2(float a, float b) { // 2x f32->bf16
  f32x2 v; v[0] = a; v[1] = b;
  bf16x2 r = __builtin_convertvector(v, bf16x2);
  union { bf16x2 b; unsigned u; } c; c.b = r; return c.u;
}
__device__ __forceinline__ float b2f(u16 v) {
  return __uint_as_float(((unsigned)v) << 16);
}
__device__ __forceinline__ bf16x8 as_frag(uint4 r) {
  union { uint4 u; bf16x8 v; } c; c.u = r; return c.v;
}

// async global->LDS, 16 bytes per lane (lds dest: wave base + lane*16)
__device__ __forceinline__ void gload_lds16(const u16* g, u16* l) {
  __builtin_amdgcn_global_load_lds(
      (const __attribute__((address_space(1))) unsigned int*)g,
      (__attribute__((address_space(3))) unsigned int*)l, 16, 0, 0);
}

// ts u8 panel base (bytes): per batch 589824; per nt prefix nt*(nt+1)/2*16384.
__device__ __forceinline__ size_t ts_base_u8(int b, int nt) {
  return (size_t)b * 589824 + (size_t)(nt * (nt + 1) / 2) * 16384;
}

// ---------------------------------------------------------------------------
// Weight pre-transpose: W (KxN f32 row-major) -> Wp bf16 panels.
// Wp elem offset = ((p*(K/32)+s)*4 + kb)*1024 + c*8 + ke
//   holds W[s*32 + kb*8 + ke][p*128 + c].
// ---------------------------------------------------------------------------
__global__ __launch_bounds__(256) void wprep(
    const float* __restrict__ W, u16* __restrict__ Wp, int K, int N)
{
  const int p = blockIdx.x, s = blockIdx.y;
  const int t = threadIdx.x;
  size_t base = ((size_t)p * (K >> 5) + s) * 4096;
  const int e0 = t * 16;
  u16 o[16];
#pragma unroll
  for (int i = 0; i < 16; ++i) {
    int e = e0 + i;
    int kb = e >> 10, r = e & 1023, c = r >> 3, ke = r & 7;
    o[i] = f2b(W[(size_t)(s * 32 + kb * 8 + ke) * N + p * 128 + c]);
  }
  *(uint4*)(Wp + base + e0)     = *(uint4*)o;
  *(uint4*)(Wp + base + e0 + 8) = *(uint4*)(o + 8);
}

// ---------------------------------------------------------------------------
// Generic bf16 GEMM: C = epi(Asrc @ W), W pre-transposed to LDS image.
// Tile 128x128x32, 256 thr = 4 waves (2x2 of 64x64). Single-buffer 2-barrier
// K-loop. 1-D grid with XCD-grouped swizzle (m204 bijective).
// AMODE: 0 bf16 A; 1 f32 A*inv[row]; 2 bf16 A*inv[row]*bf16 U; 3 image DMA.
// EPI:   0 silu->bf16 row-major; 1 f32 +ADD; 2 silu->bf16 A-image layout.
// A-image layout (per 128-row tile rt, per 32-k panel s):
//   elem offset = (rt*(K/32)+s)*4096 + kb*1024 + r*8 + ke,
//   holds A[rt*128 + r][s*32 + kb*8 + ke].
// ---------------------------------------------------------------------------
#define EPI_SILU_BF16 0
#define EPI_ADD_F32   1
#define EPI_SILU_IMG  2
#define AM_BF16   0
#define AM_F32S   1
#define AM_BF16SM 2
#define AM_IMG    3

template <int EPI, int AMODE>
__global__ __launch_bounds__(256, 2) void gemm_bf16(
    const u16* __restrict__ A, const float* __restrict__ Af,
    const float* __restrict__ inv, const u16* __restrict__ U, int ustride,
    const u16* __restrict__ Wp, void* __restrict__ C,
    const float* __restrict__ ADD, int M, int N, int K, int ncb)
{
  __shared__ u16 lA[128 * 40];
  __shared__ u16 lB[4096];

  // XCD-grouped bijective swizzle (m204)
  const int nblk = gridDim.x;
  const int q = nblk >> 3, r = nblk & 7;
  const int xcd = blockIdx.x & 7, li = blockIdx.x >> 3;
  const int work = xcd * q + (xcd < r ? xcd : r) + li;
  const int c0b = work % ncb;
  const int t0  = (work / ncb) * 128;
  const int c0  = c0b * 128;

  const int tid  = threadIdx.x;
  const int wave = tid >> 6, lane = tid & 63;
  const int wr   = (wave >> 1) * 64, wc = (wave & 1) * 64;
  const int l15  = lane & 15, l4 = lane >> 4;

  f32x4 z = {0.f, 0.f, 0.f, 0.f};
  f32x4 acc[4][4];
#pragma unroll
  for (int m = 0; m < 4; ++m)
#pragma unroll
    for (int j = 0; j < 4; ++j) acc[m][j] = z;

  const int ar = tid >> 1, ak = (tid & 1) * 16;      // A stage (non-IMG)
  const int row = t0 + ar;
  const bool arow_ok = row < M;
  float rinv = 0.f;
  if (AMODE == AM_F32S || AMODE == AM_BF16SM) if (arow_ok) rinv = inv[row];
  const u16*   ab = (AMODE == AM_BF16 || AMODE == AM_BF16SM)
                        ? A + (size_t)row * K + ak : nullptr;
  const float* af = (AMODE == AM_F32S) ? Af + (size_t)row * K + ak : nullptr;
  const u16*   um = (AMODE == AM_BF16SM) ? U + (size_t)row * ustride + ak : nullptr;

  const int ksteps = K >> 5;
  const u16* wsrc = Wp + (size_t)c0b * ksteps * 4096 + wave * 1024 + lane * 8;
  u16* ldsb = &lB[wave * 1024];
  const u16* asrc = (AMODE == AM_IMG)
      ? A + (size_t)(t0 >> 7) * ksteps * 4096 + wave * 1024 + lane * 8
      : nullptr;
  u16* ldsa = &lA[wave * 1024];

  for (int s = 0; s < ksteps; ++s) {
    // B: async DMA, 2 x 1KB per wave
    gload_lds16(wsrc,       ldsb);
    gload_lds16(wsrc + 512, ldsb + 512);
    wsrc += 4096;
    if constexpr (AMODE == AM_IMG) {
      // A: async DMA from image tile
      gload_lds16(asrc,       ldsa);
      gload_lds16(asrc + 512, ldsa + 512);
      asrc += 4096;
    } else {
      const int k0 = s * 32;
      uint4 pr[4];
      const uint4 z4 = make_uint4(0, 0, 0, 0);
      if (!arow_ok) { pr[0] = z4; pr[1] = z4; pr[2] = z4; pr[3] = z4; }
      else if constexpr (AMODE == AM_BF16) {
        pr[0] = *(const uint4*)(ab + k0);
        pr[1] = *(const uint4*)(ab + k0 + 8);
      } else if constexpr (AMODE == AM_F32S) {
        pr[0] = *(const uint4*)(af + k0);
        pr[1] = *(const uint4*)(af + k0 + 4);
        pr[2] = *(const uint4*)(af + k0 + 8);
        pr[3] = *(const uint4*)(af + k0 + 12);
      } else {
        pr[0] = *(const uint4*)(ab + k0);
        pr[1] = *(const uint4*)(ab + k0 + 8);
        pr[2] = *(const uint4*)(um + k0);
        pr[3] = *(const uint4*)(um + k0 + 8);
      }
      u16 tmp[16];
      unsigned* t32 = (unsigned*)tmp;
      if constexpr (AMODE == AM_BF16) {
        *(uint4*)tmp       = pr[0];
        *(uint4*)(tmp + 8) = pr[1];
      } else if constexpr (AMODE == AM_F32S) {
        const float* f = (const float*)pr;
#pragma unroll
        for (int i = 0; i < 8; ++i)
          t32[i] = cvt_pk2(f[2 * i] * rinv, f[2 * i + 1] * rinv);
      } else if constexpr (AMODE == AM_BF16SM) {
        const u16* a = (const u16*)pr;
        const u16* u = (const u16*)(pr + 2);
#pragma unroll
        for (int i = 0; i < 8; ++i)
          t32[i] = cvt_pk2(b2f(a[2 * i]) * rinv * b2f(u[2 * i]),
                           b2f(a[2 * i + 1]) * rinv * b2f(u[2 * i + 1]));
      }
      *(uint4*)&lA[ar * 40 + ak]     = *(uint4*)tmp;
      *(uint4*)&lA[ar * 40 + ak + 8] = *(uint4*)(tmp + 8);
    }
    __syncthreads();

    bf16x8 afr[4], bfv[4];
#pragma unroll
    for (int m = 0; m < 4; ++m) {
      if constexpr (AMODE == AM_IMG)
        afr[m] = as_frag(*(const uint4*)&lA[(l4 << 10) + (wr + m * 16 + l15) * 8]);
      else
        afr[m] = as_frag(*(const uint4*)&lA[(wr + m * 16 + l15) * 40 + l4 * 8]);
    }
#pragma unroll
    for (int j = 0; j < 4; ++j)
      bfv[j] = as_frag(*(const uint4*)&lB[(l4 << 10) + (wc + j * 16 + l15) * 8]);
#pragma unroll
    for (int m = 0; m < 4; ++m)
#pragma unroll
      for (int j = 0; j < 4; ++j)
        acc[m][j] = __builtin_amdgcn_mfma_f32_16x16x32_bf16(afr[m], bfv[j], acc[m][j], 0, 0, 0);
    __syncthreads();
  }

#pragma unroll
  for (int m = 0; m < 4; ++m) {
#pragma unroll
    for (int rr = 0; rr < 4; ++rr) {
      int orow = t0 + wr + m * 16 + l4 * 4 + rr;
      if (orow >= M) continue;
#pragma unroll
      for (int j = 0; j < 4; ++j) {
        int col = c0 + wc + j * 16 + l15;
        float y = acc[m][j][rr];
        if constexpr (EPI == EPI_SILU_BF16) {
          float s = y / (1.f + __expf(-y));          // silu
          ((u16*)C)[(size_t)orow * N + col] = f2b_n(s);
        } else if constexpr (EPI == EPI_ADD_F32) {
          size_t idx = (size_t)orow * N + col;
          ((float*)C)[idx] = y + ADD[idx];
        } else {                                     // EPI_SILU_IMG
          float s = y / (1.f + __expf(-y));
          size_t ioff = ((size_t)(t0 >> 7) * (N >> 5) + (col >> 5)) * 4096
                      + (size_t)((col >> 3) & 3) * 1024
                      + (size_t)(orow & 127) * 8 + (col & 7);
          ((u16*)C)[ioff] = f2b_n(s);
        }
      }
    }
  }
}

// ---------------------------------------------------------------------------
// pos score table: pos_s[n][m] = pos_w[n-m+1023] * (m<=n), bf16, 1024x1024.
// ---------------------------------------------------------------------------
__global__ __launch_bounds__(128) void pos_scores(
    const float* __restrict__ pos_w, u16* __restrict__ pos_s)
{
  const int n = blockIdx.x;
  const int m0 = threadIdx.x * 8;
  u16 o[8];
#pragma unroll
  for (int i = 0; i < 8; ++i) {
    int m = m0 + i;
    float v = (m <= n) ? pos_w[n - m + 1023] : 0.f;
    o[i] = f2b(v);
  }
  *(uint4*)(pos_s + (size_t)n * 1024 + m0) = *(uint4*)o;
}

// ---------------------------------------------------------------------------
// ts bucket panels (u8): for (b, nt), 128 rows x W cols, W = 128*(nt+1):
//   bucket = clip(floor(log1p|dt|*SCALE),0,128); masked (m>n) -> 129.
// ---------------------------------------------------------------------------
__global__ __launch_bounds__(256) void ts_buckets(
    const int* __restrict__ tstamp, u8* __restrict__ ts_s)
{
  const int nt = 7 - (blockIdx.x >> 6);
  const int b  = blockIdx.x & 63;
  const int W  = 128 * (nt + 1);
  const int n0 = nt * 128;
  const int tid = threadIdx.x;

  __shared__ int tsm[1024];
  for (int i = tid; i < W; i += 256) tsm[i] = tstamp[b * 1024 + i];
  __syncthreads();

  const int r = tid >> 1, h = tid & 1;
  const int n_abs = n0 + r;
  const int t_n = tstamp[b * 1024 + n_abs];
  const int half = W >> 1;
  const int c0 = h * half;
  u8* row = ts_s + ts_base_u8(b, nt) + (size_t)r * W + c0;

  for (int c = 0; c < half; c += 16) {
    u8 o[16];
#pragma unroll
    for (int i = 0; i < 16; ++i) {
      int m = c0 + c + i;
      int d = t_n - tsm[m];
      if (d < 0) d = -d;
      int bkt = (int)(log1pf((float)d) * TS_SCALE_F);   // >=0: trunc == floor
      bkt = bkt > 128 ? 128 : bkt;
      o[i] = (m <= n_abs) ? (u8)bkt : (u8)129;
    }
    *(uint4*)(row + c) = *(uint4*)o;
  }
}

// ---------------------------------------------------------------------------
// Attention as dual GEMM (round-7 form): out_pos = pos_s @ V,
// out_ts = LUT(tsU8) @ V, V gathered from proj cols [1024,1536), ragged rows
// zeroed. Output bf16, head-interleaved layout, into ws.
// ---------------------------------------------------------------------------
__global__ __launch_bounds__(256, 1) void attn_gemm(
    const u16* __restrict__ proj,      // T x 1536 bf16
    const int* __restrict__ xoff,      // B+1 (int32)
    const u16* __restrict__ pos_s,     // 1024 x 1024 bf16
    const u8*  __restrict__ tsU8,      // u8 bucket panels
    const float* __restrict__ ts_w,    // 129
    u16* __restrict__ attn_out,        // T x 1024 bf16 (ws)
    int Ttot)
{
  const int flat = blockIdx.x;
  const int nt = 7 - (flat >> 8);          // heavy tiles dispatched first
  const int rem = flat & 255;
  const int b  = rem >> 2;
  const int ct = rem & 3;

  const int off = xoff[b];
  int len = xoff[b + 1] - off;
  if (len < 0) len = 0;
  if (len > 1024) len = 1024;
  if (off < 0 || off + len > Ttot) return;
  const int n0 = nt * 128;
  if (n0 >= len) return;
  const int c0 = ct * 128;
  const int W = 128 * (nt + 1);

  __shared__ u16 lP[128 * 40];
  __shared__ u16 lT[128 * 40];
  __shared__ u16 sV[4096];
  __shared__ float s_tsw[130];

  const int tid = threadIdx.x;
  if (tid < 130) s_tsw[tid] = (tid < 129) ? ts_w[tid] : 0.f;
  __syncthreads();

  const int wave = tid >> 6, lane = tid & 63;
  const int wr = (wave >> 1) * 64, wc = (wave & 1) * 64;
  const int l15 = lane & 15, l4 = lane >> 4;

  f32x4 z = {0.f, 0.f, 0.f, 0.f};
  f32x4 accP[4][4], accT[4][4];
#pragma unroll
  for (int m = 0; m < 4; ++m)
#pragma unroll
    for (int j = 0; j < 4; ++j) { accP[m][j] = z; accT[m][j] = z; }

  const int ar = tid >> 1, ak = (tid & 1) * 16;
  const u16* pRow = pos_s + (size_t)(n0 + ar) * 1024 + ak;
  const u8*  tRow = tsU8 + ts_base_u8(b, nt) + (size_t)ar * W + ak;
  const int vk = tid >> 3, vc = (tid & 7) * 16;

  const int mEnd = (n0 + 128 < len) ? (n0 + 128) : len;

  for (int m0 = 0; m0 < mEnd; m0 += 32) {
    // ---- stage V tile (32 x 128), transposed+swizzled, ragged-zeroed ----
    {
      int mm = m0 + vk;
      uint4 v0 = make_uint4(0, 0, 0, 0), v1 = v0;
      if (mm < len) {
        const u16* src = proj + (size_t)(off + mm) * 1536 + 1024 + c0 + vc;
        v0 = *(const uint4*)src;
        v1 = *(const uint4*)(src + 8);
      }
      u16 tmp[16];
      *(uint4*)tmp       = v0;
      *(uint4*)(tmp + 8) = v1;
      const int kb = vk >> 3, ke = vk & 7;
#pragma unroll
      for (int i = 0; i < 16; ++i) {
        int col = vc + i;
        int o2 = (kb * 2048 + col * 16 + ke * 2) ^ (((col >> 3) & 7) << 4);
        *(u16*)((char*)sV + o2) = tmp[i];
      }
    }
    // ---- stage score tiles: pos streamed bf16; ts via u8 + LDS LUT ----
    {
      uint4 p0 = *(const uint4*)(pRow + m0);
      uint4 p1 = *(const uint4*)(pRow + m0 + 8);
      uint4 tb = *(const uint4*)(tRow + m0);
      const u8* bp = (const u8*)&tb;
      unsigned tt32[8];
#pragma unroll
      for (int i = 0; i < 8; ++i)
        tt32[i] = cvt_pk2(s_tsw[bp[2 * i]], s_tsw[bp[2 * i + 1]]);
      int wb = ar * 40 + ak;
      *(uint4*)&lP[wb]     = p0;
      *(uint4*)&lP[wb + 8] = p1;
      *(uint4*)&lT[wb]     = *(uint4*)tt32;
      *(uint4*)&lT[wb + 8] = *(uint4*)(tt32 + 4);
    }
    __syncthreads();

    bf16x8 ap[4], at[4], bv[4];
#pragma unroll
    for (int m = 0; m < 4; ++m) {
      ap[m] = as_frag(*(const uint4*)&lP[(wr + m * 16 + l15) * 40 + l4 * 8]);
      at[m] = as_frag(*(const uint4*)&lT[(wr + m * 16 + l15) * 40 + l4 * 8]);
    }
#pragma unroll
    for (int j = 0; j < 4; ++j) {
      int col = wc + j * 16 + l15;
      int o2 = (l4 * 2048 + col * 16) ^ (((col >> 3) & 7) << 4);
      bv[j] = as_frag(*(const uint4*)((char*)sV + o2));
    }
#pragma unroll
    for (int m = 0; m < 4; ++m)
#pragma unroll
      for (int j = 0; j < 4; ++j) {
        accP[m][j] = __builtin_amdgcn_mfma_f32_16x16x32_bf16(ap[m], bv[j], accP[m][j], 0, 0, 0);
        accT[m][j] = __builtin_amdgcn_mfma_f32_16x16x32_bf16(at[m], bv[j], accT[m][j], 0, 0, 0);
      }
    __syncthreads();
  }

  // ---- store bf16 with head-interleaved combined layout ----
#pragma unroll
  for (int m = 0; m < 4; ++m)
#pragma unroll
    for (int r = 0; r < 4; ++r) {
      int n = n0 + wr + m * 16 + l4 * 4 + r;
      if (n >= len) continue;
      size_t t = (size_t)(off + n);
#pragma unroll
      for (int j = 0; j < 4; ++j) {
        int hd = c0 + wc + j * 16 + l15;            // 0..511
        int colP = ((hd >> 6) << 7) + (hd & 63);    // h*128 + d
        attn_out[t * 1024 + colP]      = f2b_n(accP[m][j][r]);
        attn_out[t * 1024 + colP + 64] = f2b_n(accT[m][j][r]);
      }
    }
}

// ---------------------------------------------------------------------------
// Per-row inv-rms: inv[row] = rsqrt(mean(row^2) + eps). 4 rows/block (1/wave).
// WIMG (D=512, F32IN only): also write bf16(row*inv) in A-image layout.
// ---------------------------------------------------------------------------
template <int D, bool F32IN, bool WIMG>
__global__ __launch_bounds__(256) void row_ss(
    const void* __restrict__ in, float* __restrict__ inv, u16* __restrict__ img,
    int T)
{
  const int row = blockIdx.x * 4 + (threadIdx.x >> 6);
  const int lane = threadIdx.x & 63;
  if (row >= T) return;
  float ss = 0.f;
  float v8[8];
  if constexpr (F32IN) {
    const float* r = (const float*)in + (size_t)row * D;
    if constexpr (WIMG) {            // D == 512: lane holds k = lane*8 .. +7
      float4 a = *(const float4*)(r + lane * 8);
      float4 b = *(const float4*)(r + lane * 8 + 4);
      v8[0] = a.x; v8[1] = a.y; v8[2] = a.z; v8[3] = a.w;
      v8[4] = b.x; v8[5] = b.y; v8[6] = b.z; v8[7] = b.w;
#pragma unroll
      for (int k = 0; k < 8; ++k) ss += v8[k] * v8[k];
    } else {
#pragma unroll
      for (int i = lane * 4; i < D; i += 256) {
        float4 v = *(const float4*)(r + i);
        ss += v.x * v.x + v.y * v.y + v.z * v.z + v.w * v.w;
      }
    }
  } else {
    const u16* r = (const u16*)in + (size_t)row * D;
#pragma unroll
    for (int i = lane * 8; i < D; i += 512) {
      uint4 v = *(const uint4*)(r + i);
      const u16* q = (const u16*)&v;
#pragma unroll
      for (int k = 0; k < 8; ++k) { float f = b2f(q[k]); ss += f * f; }
    }
  }
#pragma unroll
  for (int o = 32; o > 0; o >>= 1) ss += __shfl_down(ss, o, 64);
  ss = __shfl(ss, 0, 64);
  float rv = rsqrtf(ss / (float)D + 1e-6f);
  if (lane == 0) inv[row] = rv;
  if constexpr (WIMG) {
    unsigned w[4];
#pragma unroll
    for (int i = 0; i < 4; ++i)
      w[i] = cvt_pk2(v8[2 * i] * rv, v8[2 * i + 1] * rv);
    size_t off = (size_t)(row >> 7) * ((D >> 5) * 4096)
               + (size_t)(lane >> 2) * 4096 + (size_t)(lane & 3) * 1024
               + (size_t)(row & 127) * 8;
    *(uint4*)(img + off) = *(uint4*)w;
  }
}

// ---------------------------------------------------------------------------
extern "C" void kernel_launch(void* const* d_in, const int* in_sizes, int n_in,
                              void* d_out, int out_size, void* d_ws, size_t ws_size,
                              hipStream_t stream)
{
  const float* x      = (const float*)d_in[0];
  const int*   xoff   = (const int*)d_in[1];    // int32 per harness contract
  const int*   tstamp = (const int*)d_in[2];    // int32 per harness contract
  // d_in[3] = invalid_attn_mask (tril) -- implied by causal masking, unused
  const float* uv     = (const float*)d_in[4];
  const float* pos_w  = (const float*)d_in[5];
  const float* ts_w   = (const float*)d_in[6];
  const float* w_ams  = (const float*)d_in[7];
  const float* w1     = (const float*)d_in[8];
  const float* w2     = (const float*)d_in[9];
  const int T = in_sizes[0] / 512;
  const int nrow = (T + 127) / 128;

  char* ws = (char*)d_ws;
  size_t o = 0;
  auto take = [&](size_t bytes) { size_t r = o; o += (bytes + 255) & ~(size_t)255; return r; };

  // --- static small buffers ---
  u16* uvb    = (u16*)(ws + take((size_t)512 * 1536 * 2));
  u16* wamsb  = (u16*)(ws + take((size_t)1024 * 512 * 2));
  u16* w1b    = (u16*)(ws + take((size_t)512 * 2048 * 2));
  u16* w2b    = (u16*)(ws + take((size_t)2048 * 512 * 2));
  u16* posS   = (u16*)(ws + take((size_t)1024 * 1024 * 2));   // 2 MB

  // --- main regions ---
  size_t o_ts   = take((size_t)64 * 589824 + 256); // tsU8 37.7 MB (+overread pad)
  size_t o_attn = take((size_t)T * 1024 * 2);      // attn bf16 83.9 [attn->F]
  size_t o_proj = take((size_t)T * 1536 * 2);      // proj 125.8 [B->F]
  float* invX = (float*)(ws + take((size_t)T * 4));
  float* invA = (float*)(ws + take((size_t)T * 4));
  float* invH = (float*)(ws + take((size_t)T * 4));

  u8*  tsU8  = (u8*)(ws + o_ts);
  u16* attnS = (u16*)(ws + o_attn);
  u16* proj  = (u16*)(ws + o_proj);
  u16* midI  = (u16*)(ws + o_ts);     // mid A-IMAGE, nrow*64*4096 u16 (~168MB)
                                      // [H->I]; aliases tsU8+attnS+proj-head
                                      // (all dead by H)
  u16*   xb  = (u16*)d_out;           // x*invX bf16 A-image (42MB), dead by F
  float* h   = (float*)d_out;         // h lives in d_out (F->I), out in-place

  // If the workspace is too small, launch nothing: clean absmax failure.
  if (ws_size < o) return;

  // weight pre-transpose f32 -> bf16 LDS-image panels
  wprep<<<dim3(12, 16), 256, 0, stream>>>(uv,    uvb,   512,  1536);
  wprep<<<dim3(4, 32),  256, 0, stream>>>(w_ams, wamsb, 1024, 512);
  wprep<<<dim3(16, 16), 256, 0, stream>>>(w1,    w1b,   512,  2048);
  wprep<<<dim3(4, 64),  256, 0, stream>>>(w2,    w2b,   2048, 512);

  // score precompute
  pos_scores<<<1024, 128, 0, stream>>>(pos_w, posS);
  ts_buckets<<<512, 256, 0, stream>>>(tstamp, tsU8);

  // invX over x + xb image write (into d_out scratch)
  row_ss<512, true, true><<<(T + 3) / 4, 256, 0, stream>>>(x, invX, xb, T);

  // B: proj = silu(xb @ uv)   (T x 1536), A fully DMA-staged
  gemm_bf16<EPI_SILU_BF16, AM_IMG><<<12 * nrow, 256, 0, stream>>>(
      xb, nullptr, nullptr, nullptr, 0, uvb, proj, nullptr, T, 1536, 512, 12);

  // attention -> attnS (ws)
  attn_gemm<<<64 * 32, 256, 0, stream>>>(proj, xoff, posS, tsU8, ts_w, attnS, T);

  // invA over attn
  row_ss<1024, false, false><<<(T + 3) / 4, 256, 0, stream>>>(attnS, invA, nullptr, T);

  // F: h = x + ((attn*invA*u) @ w_ams)   (T x 512) -> d_out
  gemm_bf16<EPI_ADD_F32, AM_BF16SM><<<4 * nrow, 256, 0, stream>>>(
      attnS, nullptr, invA, proj, 1536, wamsb, h, x, T, 512, 1024, 4);

  // invH over h
  row_ss<512, true, false><<<(T + 3) / 4, 256, 0, stream>>>(h, invH, nullptr, T);

  // H: midI = silu((h*invH) @ w1) in A-image layout   (T x 2048)
  gemm_bf16<EPI_SILU_IMG, AM_F32S><<<16 * nrow, 256, 0, stream>>>(
      nullptr, h, invH, nullptr, 0, w1b, midI, nullptr, T, 2048, 512, 16);

  // I: out = h + midI @ w2   (T x 512), A fully DMA-staged, in-place on d_out
  gemm_bf16<EPI_ADD_F32, AM_IMG><<<4 * nrow, 256, 0, stream>>>(
      midI, nullptr, nullptr, nullptr, 0, w2b, h, h, T, 512, 2048, 4);
}